// Round 6
// baseline (950.130 us; speedup 1.0000x reference)
//
#include <hip/hip_runtime.h>
#include <hip/hip_bf16.h>

// CONCATNet forward. B=512 NW=256 NS=8 P=32 D=512 H=16 QK=32 A=34
// R11: 256x128 tile, 128x64 per wave (acc 8x4) in gemm_mfma.
//  - R10 model closure: per CU per K-step, LDS-read occupancy 96 ds_read_b128
//    x 12cy = 1152cy vs MFMA 310cy/SIMD -> predicted MfmaUtil 27% == measured
//    27.4%. The GEMM is LDS-READ-BOUND. Fix: bigger per-wave accumulator.
//    Wave now 128x64 (acc 8x4): 16 frag reads per 64 MFMA = 0.25 reads/MFMA
//    (was 0.375) -> -33% on the binding resource. LDS 64KB, 2 blocks/CU.
//    Accumulation order per element is bit-identical to R10.
//  - gatherG merged into prologue grid (idxw computed inline from lhw);
//    one fewer serial launch.
// R10: BK=64 (halved per-K-step fixed drain cost).
// R9: fp16 2-pass split GEMM (A single fp16, W split hi/lo). absmax 2^-10.
// R6: fused split passes + bijective XCD block remap (FETCH 447->137MB).
// action_mask arrives as int32 (harness widens bool).

#define B_  512
#define NW_ 256
#define NS_ 8
#define P_  32
#define D_  512
#define H_  16
#define QK_ 32
#define A_  34

typedef __attribute__((ext_vector_type(8))) _Float16 half8;
typedef __attribute__((ext_vector_type(4))) float floatx4;

// ---------------------------------------------------------------- fp16 helpers
__device__ __forceinline__ unsigned short f16b(float x) {
    _Float16 h = (_Float16)x;
    union { _Float16 f; unsigned short u; } c; c.f = h; return c.u;
}
__device__ __forceinline__ void f16_split(float x, unsigned short& hi, unsigned short& lo) {
    _Float16 h = (_Float16)x;
    _Float16 l = (_Float16)(x - (float)h);
    union { _Float16 f; unsigned short u; } c;
    c.f = h; hi = c.u; c.f = l; lo = c.u;
}

__device__ __forceinline__ void gload16(const void* g, void* l) {
    __builtin_amdgcn_global_load_lds(
        (const __attribute__((address_space(1))) void*)g,
        (__attribute__((address_space(3))) void*)l, 16, 0, 0);
}

// ---------------------------------------------------------------- MFMA GEMM
// A buffers: single fp16, row stride 512 shorts.
// W buffers: split fp16, row stride 1024 shorts (hi at +0, lo at +512).
struct Pair { const unsigned short* a; const unsigned short* w; };
struct GemmCfg {
    Pair pr[2];
    int npair;
    float* C;
    int ldc;
    const float* r1row;
    const float* r1col;
    int fuseE;
    const float* colemb;
    const float* c_pm;
    const float* remain;
    const int* idxs;
    unsigned short* Epack;
};

__global__ __launch_bounds__(256) void gemm_mfma(GemmCfg cfg)
{
    // 256x128 tile, BK=64: A 256x64 shorts = 32 KB; WH/WL 128x64 = 16 KB each
    __shared__ __align__(16) unsigned short As [256 * 64];
    __shared__ __align__(16) unsigned short WsH[128 * 64];
    __shared__ __align__(16) unsigned short WsL[128 * 64];

    const int tid  = threadIdx.x;

    // XCD-aware bijective block remap (m204)
    int lid = blockIdx.y * gridDim.x + blockIdx.x;
    {
        const int nwg = gridDim.x * gridDim.y;
        const int xcd = lid & 7, o = lid >> 3;
        const int qq = nwg >> 3, rr = nwg & 7;
        lid = (xcd < rr ? xcd * (qq + 1) : rr * (qq + 1) + (xcd - rr) * qq) + o;
    }
    const int m0 = (lid / gridDim.x) * 256;
    const int n0 = (lid % gridDim.x) * 128;

    const int wave = tid >> 6;
    const int lane = tid & 63;
    const int wr   = wave >> 1;      // row half: 128 rows
    const int wc   = wave & 1;       // col half: 64 cols
    // staging: 256 threads cover 32 rows x 8 chunks per round
    const int srow  = tid >> 3;
    const int lpart = (((tid & 7) ^ (srow & 7)) << 3); // permuted global chunk

    floatx4 acc[8][4];
#pragma unroll
    for (int i = 0; i < 8; i++)
#pragma unroll
        for (int j = 0; j < 4; j++) acc[i][j] = (floatx4)0.f;

    const int q = lane >> 4;
    const int r = lane & 15;
    // stored position of global chunk (s*4+q) in row (..+r): XOR with row&7
    const int qs0 = (((q    ) ^ (r & 7)) << 3);
    const int qs1 = (((q + 4) ^ (r & 7)) << 3);

    for (int pi = 0; pi < cfg.npair; ++pi) {
        const unsigned short* Ab = cfg.pr[pi].a + (size_t)(m0 + srow) * 512 + lpart;
        const unsigned short* Wb = cfg.pr[pi].w + (size_t)(n0 + srow) * 1024 + lpart;
        for (int k0 = 0; k0 < 512; k0 += 64) {
            __syncthreads();
#pragma unroll
            for (int rd = 0; rd < 8; rd++)
                gload16(Ab + (size_t)rd * (32 * 512) + k0, &As[rd * 2048 + tid * 8]);
#pragma unroll
            for (int rd = 0; rd < 4; rd++) {
                gload16(Wb + (size_t)rd * (32 * 1024) + k0,       &WsH[rd * 2048 + tid * 8]);
                gload16(Wb + (size_t)rd * (32 * 1024) + k0 + 512, &WsL[rd * 2048 + tid * 8]);
            }
            __syncthreads();

#pragma unroll
            for (int s = 0; s < 2; s++) {
                const int qs = s ? qs1 : qs0;
                half8 af[8], wh[4], wl[4];
#pragma unroll
                for (int i = 0; i < 8; i++)
                    af[i] = *(const half8*)&As[(wr * 128 + i * 16 + r) * 64 + qs];
#pragma unroll
                for (int j = 0; j < 4; j++) {
                    wh[j] = *(const half8*)&WsH[(wc * 64 + j * 16 + r) * 64 + qs];
                    wl[j] = *(const half8*)&WsL[(wc * 64 + j * 16 + r) * 64 + qs];
                }
                // A x W_hi
#pragma unroll
                for (int i = 0; i < 8; i++)
#pragma unroll
                    for (int j = 0; j < 4; j++)
                        acc[i][j] = __builtin_amdgcn_mfma_f32_16x16x32_f16(
                            af[i], wh[j], acc[i][j], 0, 0, 0);
                // A x W_lo
#pragma unroll
                for (int i = 0; i < 8; i++)
#pragma unroll
                    for (int j = 0; j < 4; j++)
                        acc[i][j] = __builtin_amdgcn_mfma_f32_16x16x32_f16(
                            af[i], wl[j], acc[i][j], 0, 0, 0);
            }
        }
    }

    if (cfg.fuseE) {
#pragma unroll
        for (int j = 0; j < 4; j++) {
            const int col = n0 + wc * 64 + j * 16 + r;
            const float cpm = cfg.c_pm[col];
#pragma unroll
            for (int i = 0; i < 8; i++) {
                const int rowb = m0 + wr * 128 + i * 16 + q * 4;
#pragma unroll
                for (int reg = 0; reg < 4; reg++) {
                    const int m = rowb + reg;
                    const int b = m / A_;
                    const int a = m - b * A_;
                    float v = 0.f;
                    if (a >= 2) {
                        const int p = a - 2;
                        const int s = cfg.idxs[b * P_ + p];
                        v = acc[i][j][reg]
                          + cfg.colemb[((size_t)(b * NS_ + s)) * 512 + col]
                          + cfg.remain[b * P_ + p] * cpm;
                    }
                    cfg.C[(size_t)m * 512 + col] = v;
                    cfg.Epack[(size_t)m * 512 + col] = f16b(v);
                }
            }
        }
    } else {
#pragma unroll
        for (int j = 0; j < 4; j++) {
            const int col = n0 + wc * 64 + j * 16 + r;
            const float r1c = cfg.r1col ? cfg.r1col[col] : 0.f;
#pragma unroll
            for (int i = 0; i < 8; i++) {
                const int rowb = m0 + wr * 128 + i * 16 + q * 4;
#pragma unroll
                for (int reg = 0; reg < 4; reg++) {
                    float v = acc[i][j][reg];
                    if (cfg.r1row) v += cfg.r1row[rowb + reg] * r1c;
                    cfg.C[(size_t)(rowb + reg) * cfg.ldc + col] = v;
                }
            }
        }
    }
}

// ---------------------------------------------------------------- fp32 GEMM (small)
#define BM 64
#define BN 64
#define BK 32
__global__ __launch_bounds__(256) void gemm_nt(
    const float* __restrict__ A, int lda,
    const float* __restrict__ W, int ldw,
    float* __restrict__ C, int ldc,
    int K,
    const float* __restrict__ bias,
    int relu)
{
    __shared__ float As[BK][BM + 4];
    __shared__ float Wsm[BK][BN + 4];

    const int tid = threadIdx.x;
    const int m0 = blockIdx.y * BM;
    const int n0 = blockIdx.x * BN;
    const int ty = tid >> 4;
    const int tx = tid & 15;
    const int lrow = tid >> 2;
    const int lcol = (tid & 3) << 3;

    float acc[4][4];
#pragma unroll
    for (int i = 0; i < 4; i++)
#pragma unroll
        for (int j = 0; j < 4; j++) acc[i][j] = 0.f;

    const float* Ablk = A + (size_t)m0 * lda;
    const float* Wblk = W + (size_t)n0 * ldw;

    for (int k0 = 0; k0 < K; k0 += BK) {
        const float* ap = Ablk + (size_t)lrow * lda + k0 + lcol;
        float4 a0 = *(const float4*)(ap);
        float4 a1 = *(const float4*)(ap + 4);
        const float* wp = Wblk + (size_t)lrow * ldw + k0 + lcol;
        float4 w0 = *(const float4*)(wp);
        float4 w1 = *(const float4*)(wp + 4);

        __syncthreads();
        As[lcol + 0][lrow] = a0.x; As[lcol + 1][lrow] = a0.y;
        As[lcol + 2][lrow] = a0.z; As[lcol + 3][lrow] = a0.w;
        As[lcol + 4][lrow] = a1.x; As[lcol + 5][lrow] = a1.y;
        As[lcol + 6][lrow] = a1.z; As[lcol + 7][lrow] = a1.w;
        Wsm[lcol + 0][lrow] = w0.x; Wsm[lcol + 1][lrow] = w0.y;
        Wsm[lcol + 2][lrow] = w0.z; Wsm[lcol + 3][lrow] = w0.w;
        Wsm[lcol + 4][lrow] = w1.x; Wsm[lcol + 5][lrow] = w1.y;
        Wsm[lcol + 6][lrow] = w1.z; Wsm[lcol + 7][lrow] = w1.w;
        __syncthreads();

#pragma unroll
        for (int k = 0; k < BK; k++) {
            const float4 av = *(const float4*)(&As[k][ty << 2]);
            const float4 wv = *(const float4*)(&Wsm[k][tx << 2]);
            acc[0][0] += av.x * wv.x; acc[0][1] += av.x * wv.y;
            acc[0][2] += av.x * wv.z; acc[0][3] += av.x * wv.w;
            acc[1][0] += av.y * wv.x; acc[1][1] += av.y * wv.y;
            acc[1][2] += av.y * wv.z; acc[1][3] += av.y * wv.w;
            acc[2][0] += av.z * wv.x; acc[2][1] += av.z * wv.y;
            acc[2][2] += av.z * wv.z; acc[2][3] += av.z * wv.w;
            acc[3][0] += av.w * wv.x; acc[3][1] += av.w * wv.y;
            acc[3][2] += av.w * wv.z; acc[3][3] += av.w * wv.w;
        }
    }

    const int mbase = m0 + (ty << 2);
    const int nbase = n0 + (tx << 2);
    float4 bv = make_float4(0.f, 0.f, 0.f, 0.f);
    if (bias) bv = *(const float4*)(bias + nbase);

#pragma unroll
    for (int i = 0; i < 4; i++) {
        float* cp = C + (size_t)(mbase + i) * ldc + nbase;
        float4 v = make_float4(acc[i][0], acc[i][1], acc[i][2], acc[i][3]);
        if (bias) { v.x += bv.x; v.y += bv.y; v.z += bv.z; v.w += bv.w; }
        if (relu) {
            v.x = fmaxf(v.x, 0.f); v.y = fmaxf(v.y, 0.f);
            v.z = fmaxf(v.z, 0.f); v.w = fmaxf(v.w, 0.f);
        }
        *(float4*)cp = v;
    }
}

// ---------------------------------------------------------------- ctx 3-in-1
struct Ctx3Cfg {
    const float* A0; const float* A1; const float* A2;
    const float* W0; const float* W1; const float* W2;
    float* C;
};
__global__ __launch_bounds__(256) void ctx3_kernel(Ctx3Cfg cfg)
{
    const int z = blockIdx.z;
    const float* A = (z == 0) ? cfg.A0 : (z == 1) ? cfg.A1 : cfg.A2;
    const float* W = (z == 0) ? cfg.W0 : (z == 1) ? cfg.W1 : cfg.W2;
    const int K = (z == 0) ? 1024 : 512;
    const int lda = K, ldw = K;
    float* C = cfg.C + z * 512;
    const int ldc = 1536;

    __shared__ float As[BK][BM + 4];
    __shared__ float Wsm[BK][BN + 4];

    const int tid = threadIdx.x;
    const int m0 = blockIdx.y * BM;
    const int n0 = blockIdx.x * BN;
    const int ty = tid >> 4;
    const int tx = tid & 15;
    const int lrow = tid >> 2;
    const int lcol = (tid & 3) << 3;

    float acc[4][4];
#pragma unroll
    for (int i = 0; i < 4; i++)
#pragma unroll
        for (int j = 0; j < 4; j++) acc[i][j] = 0.f;

    const float* Ablk = A + (size_t)m0 * lda;
    const float* Wblk = W + (size_t)n0 * ldw;

    for (int k0 = 0; k0 < K; k0 += BK) {
        const float* ap = Ablk + (size_t)lrow * lda + k0 + lcol;
        float4 a0 = *(const float4*)(ap);
        float4 a1 = *(const float4*)(ap + 4);
        const float* wp = Wblk + (size_t)lrow * ldw + k0 + lcol;
        float4 w0 = *(const float4*)(wp);
        float4 w1 = *(const float4*)(wp + 4);

        __syncthreads();
        As[lcol + 0][lrow] = a0.x; As[lcol + 1][lrow] = a0.y;
        As[lcol + 2][lrow] = a0.z; As[lcol + 3][lrow] = a0.w;
        As[lcol + 4][lrow] = a1.x; As[lcol + 5][lrow] = a1.y;
        As[lcol + 6][lrow] = a1.z; As[lcol + 7][lrow] = a1.w;
        Wsm[lcol + 0][lrow] = w0.x; Wsm[lcol + 1][lrow] = w0.y;
        Wsm[lcol + 2][lrow] = w0.z; Wsm[lcol + 3][lrow] = w0.w;
        Wsm[lcol + 4][lrow] = w1.x; Wsm[lcol + 5][lrow] = w1.y;
        Wsm[lcol + 6][lrow] = w1.z; Wsm[lcol + 7][lrow] = w1.w;
        __syncthreads();

#pragma unroll
        for (int k = 0; k < BK; k++) {
            const float4 av = *(const float4*)(&As[k][ty << 2]);
            const float4 wv = *(const float4*)(&Wsm[k][tx << 2]);
            acc[0][0] += av.x * wv.x; acc[0][1] += av.x * wv.y;
            acc[0][2] += av.x * wv.z; acc[0][3] += av.x * wv.w;
            acc[1][0] += av.y * wv.x; acc[1][1] += av.y * wv.y;
            acc[1][2] += av.y * wv.z; acc[1][3] += av.y * wv.w;
            acc[2][0] += av.z * wv.x; acc[2][1] += av.z * wv.y;
            acc[2][2] += av.z * wv.z; acc[2][3] += av.z * wv.w;
            acc[3][0] += av.w * wv.x; acc[3][1] += av.w * wv.y;
            acc[3][2] += av.w * wv.z; acc[3][3] += av.w * wv.w;
        }
    }

    const int mbase = m0 + (ty << 2);
    const int nbase = n0 + (tx << 2);
#pragma unroll
    for (int i = 0; i < 4; i++) {
        float* cp = C + (size_t)(mbase + i) * ldc + nbase;
        *(float4*)cp = make_float4(acc[i][0], acc[i][1], acc[i][2], acc[i][3]);
    }
}

// ---------------------------------------------------------------- fused prologue
// blocks [0,4096): packW | [4096,8192): packcol | [8192,8208): cvec |
// [8208,8464): prep (2 batch rows per block) | [8464,25872): gatherG
struct ProCfg {
    const float* Wp; const float* Wk; const float* Wv; const float* Wsh;
    unsigned short* Wpack;
    const float* enc_col; unsigned short* Cpack;
    const float* W_dyn; const float* W_time; float* cvec;
    const float* clockp; const float* lpet;
    const int* loc_id; const int* robot_loc; const int* lhw; const int* lstage;
    float* dallA; float* remain; int* idxs;
    const float* enc_row; const int* ll1; const int* ll2;
    unsigned short* Gpack; float* Gll;
};
__global__ __launch_bounds__(128) void prologue_kernel(ProCfg c)
{
    const int blk = blockIdx.x;
    const int tid = threadIdx.x;
    if (blk < 4096) {
        // ---- packW (fp16 split: hi + lo halves)
        const int row = blk & 511;
        const int ms = blk >> 9;
        const int mat = ms >> 1, seg = ms & 1;
        const int d = tid * 4;
        const float* src = (mat == 0 ? c.Wp : mat == 1 ? c.Wk : mat == 2 ? c.Wv : c.Wsh)
                           + (size_t)row * 1536 + seg * 512 + d;
        const float4 v = *(const float4*)src;
        unsigned short h0, h1, h2, h3, l0, l1, l2, l3;
        f16_split(v.x, h0, l0); f16_split(v.y, h1, l1);
        f16_split(v.z, h2, l2); f16_split(v.w, h3, l3);
        unsigned short* dst;
        if (mat == 0) {
            dst = c.Wpack + (size_t)seg * 524288 + (size_t)row * 1024 + d;
        } else {
            const int rr = (mat - 1) * 512 + row;
            dst = c.Wpack + 1048576 + (size_t)seg * 1572864 + (size_t)rr * 1024 + d;
        }
        *(ushort4*)dst = make_ushort4(h0, h1, h2, h3);
        *(ushort4*)(dst + 512) = make_ushort4(l0, l1, l2, l3);
    } else if (blk < 8192) {
        // ---- packcol (single fp16)
        const int row = blk - 4096;
        const int d = tid * 4;
        const float4 v = *(const float4*)(c.enc_col + (size_t)row * 512 + d);
        unsigned short* dp = c.Cpack + (size_t)row * 512 + d;
        *(ushort4*)dp = make_ushort4(f16b(v.x), f16b(v.y), f16b(v.z), f16b(v.w));
    } else if (blk < 8208) {
        // ---- cvec
        const int id = (blk - 8192) * 128 + tid;
        const int vec = id >> 9;
        const int h = id & 511;
        float s = 0.f;
        if (vec == 0) {
            const float* wp = c.Wp + (size_t)h * 1536 + 1024;
            for (int j = 0; j < 512; j++) s += c.W_dyn[j * 2] * wp[j];
        } else {
            const float* Wm = (vec == 1) ? c.Wk : (vec == 2) ? c.Wv : c.Wsh;
            const float* wp = Wm + (size_t)h * 1536 + 1024;
            for (int j = 0; j < 512; j++) s += c.W_time[j] * wp[j];
        }
        c.cvec[id] = s;
    } else if (blk < 8464) {
        // ---- prep (2 batch rows / block)
        const int b = (blk - 8208) * 2 + (tid >> 6);
        const int t = tid & 63;
        const float ck = c.clockp[b];
        const int rb = c.robot_loc[b];
        if (t < P_) {
            const float endt = c.lpet[b * P_ + t];
            const int lid = c.loc_id[b * P_ + t];
            const float pk = ck + 3.f * (lid != rb ? 1.f : 0.f);
            c.dallA[b * A_ + 2 + t] = (fmaxf(endt, pk) + 9.f - ck) * (1.f / 300.f);
            c.remain[b * P_ + t] = fmaxf(endt - ck, 0.f) * (1.f / 300.f);
            c.idxs[b * P_ + t] = c.lstage[b * P_ + t] - 1;
        } else if (t == P_) {
            const float d0 = (3.f * (rb != 0 ? 1.f : 0.f) + 9.f) * (1.f / 300.f);
            c.dallA[b * A_ + 0] = d0;
            c.dallA[b * A_ + 1] = d0;
        }
    } else {
        // ---- gatherG (idxw computed inline from lhw)
        const int ba = blk - 8464;
        const int b = ba / A_, a = ba % A_;
        const int d = tid * 4;
        int row;
        if (a == 0) row = c.ll1[b];
        else if (a == 1) row = c.ll2[b];
        else {
            const int w = c.lhw[b * P_ + a - 2];
            row = (w >= 0) ? w : NW_;
        }
        float4 v = make_float4(0.f, 0.f, 0.f, 0.f);
        if (row < NW_) v = *(const float4*)(c.enc_row + ((size_t)b * NW_ + row) * D_ + d);
        unsigned short* dp = c.Gpack + (size_t)ba * 512 + d;
        *(ushort4*)dp = make_ushort4(f16b(v.x), f16b(v.y), f16b(v.z), f16b(v.w));
        if (a < 2) *(float4*)(c.Gll + (size_t)b * 1024 + a * 512 + d) = v;
    }
}

// ---------------------------------------------------------------- mean + rb gather
__global__ __launch_bounds__(128) void meanrb_kernel(
    const float* __restrict__ E, const int* __restrict__ robot_loc,
    float* __restrict__ Xpm, float* __restrict__ Xrb)
{
    const int b = blockIdx.x;
    const int d = threadIdx.x * 4;
    const float* ep = E + ((size_t)b * A_ + 2) * D_ + d;
    float4 acc = make_float4(0.f, 0.f, 0.f, 0.f);
    for (int p = 0; p < P_; p++) {
        const float4 v = *(const float4*)(ep + (size_t)p * D_);
        acc.x += v.x; acc.y += v.y; acc.z += v.z; acc.w += v.w;
    }
    const float inv = 1.f / (float)P_;
    acc.x *= inv; acc.y *= inv; acc.z *= inv; acc.w *= inv;
    *(float4*)(Xpm + (size_t)b * D_ + d) = acc;
    const int rb = robot_loc[b];
    *(float4*)(Xrb + (size_t)b * D_ + d) =
        *(const float4*)(E + ((size_t)b * A_ + 2 + rb) * D_ + d);
}

// ---------------------------------------------------------------- attention
// linear grid 8192 = B*H, XCD chunk remap so all 16 heads of a batch land on
// the same XCD's L2 (they share that batch's K/V lines).
__global__ __launch_bounds__(64) void attn_kernel(
    const float* __restrict__ Q, const float* __restrict__ KVS,
    const int* __restrict__ mask, float* __restrict__ OUT)
{
    const int L = blockIdx.x;
    const int lid = ((L & 7) << 10) + (L >> 3);   // 8192 = 8 * 1024, bijective
    const int b = lid >> 4;
    const int h = lid & 15;
    const int lane = threadIdx.x;
    __shared__ float w[A_];
    float s;
    if (lane < A_) {
        const float* qp = Q + (size_t)b * D_ + h * QK_;
        const float* kp = KVS + ((size_t)b * A_ + lane) * 1536 + h * QK_;
        float acc = 0.f;
#pragma unroll
        for (int i = 0; i < QK_; i += 4) {
            const float4 qv = *(const float4*)(qp + i);
            const float4 kv = *(const float4*)(kp + i);
            acc += qv.x * kv.x + qv.y * kv.y + qv.z * kv.z + qv.w * kv.w;
        }
        s = acc * 0.17677669529663687f;
        if (!mask[b * A_ + lane]) s += -1e10f;
    } else {
        s = -1e30f;
    }
    float m = s;
    for (int o = 32; o; o >>= 1) m = fmaxf(m, __shfl_xor(m, o));
    float p = (lane < A_) ? expf(s - m) : 0.f;
    float sum = p;
    for (int o = 32; o; o >>= 1) sum += __shfl_xor(sum, o);
    if (lane < A_) w[lane] = p / sum;
    __syncthreads();
    if (lane < QK_) {
        const float* vp = KVS + (size_t)b * A_ * 1536 + 512 + h * QK_ + lane;
        float acc = 0.f;
#pragma unroll 2
        for (int a = 0; a < A_; a++) acc += w[a] * vp[(size_t)a * 1536];
        OUT[(size_t)b * D_ + h * QK_ + lane] = acc;
    }
}

// ---------------------------------------------------------------- final
__global__ __launch_bounds__(320) void final_kernel(
    const float* __restrict__ MH, const float* __restrict__ KVS,
    const int* __restrict__ mask, float* __restrict__ out)
{
    const int b = blockIdx.x;
    const int t = threadIdx.x;
    __shared__ float mh[D_];
    __shared__ float sc[A_];
    for (int i = t; i < D_; i += 320) mh[i] = MH[(size_t)b * D_ + i];
    __syncthreads();
    const int a = t >> 3;
    const int part = t & 7;
    float s = 0.f;
    if (a < A_) {
        const float* sp = KVS + ((size_t)b * A_ + a) * 1536 + 1024 + part * 64;
        const float* mp = mh + part * 64;
#pragma unroll
        for (int i = 0; i < 64; i += 4) {
            const float4 v = *(const float4*)(sp + i);
            s += mp[i] * v.x + mp[i + 1] * v.y + mp[i + 2] * v.z + mp[i + 3] * v.w;
        }
    }
    s += __shfl_down(s, 4, 8);
    s += __shfl_down(s, 2, 8);
    s += __shfl_down(s, 1, 8);
    if (a < A_ && part == 0) {
        float v = 10.f * tanhf(s * 0.044194173824159216f);
        if (!mask[b * A_ + a]) v += -1e10f;
        sc[a] = v;
    }
    __syncthreads();
    if (t < 64) {
        float x = (t < A_) ? sc[t] : -1e30f;
        float m = x;
        for (int o = 32; o; o >>= 1) m = fmaxf(m, __shfl_xor(m, o));
        float p = (t < A_) ? expf(x - m) : 0.f;
        float sum = p;
        for (int o = 32; o; o >>= 1) sum += __shfl_xor(sum, o);
        if (t < A_) out[(size_t)b * A_ + t] = p / sum;
    }
}

// ---------------------------------------------------------------- launcher
extern "C" void kernel_launch(void* const* d_in, const int* in_sizes, int n_in,
                              void* d_out, int out_size, void* d_ws, size_t ws_size,
                              hipStream_t stream)
{
    const float* enc_row = (const float*)d_in[0];
    const float* enc_col = (const float*)d_in[1];
    const float* clockp  = (const float*)d_in[2];
    const float* lpet    = (const float*)d_in[3];
    const int* loc_id    = (const int*)d_in[4];
    const int* robot_loc = (const int*)d_in[5];
    const int* lhw       = (const int*)d_in[6];
    const int* lstage    = (const int*)d_in[7];
    const int* ll1       = (const int*)d_in[8];
    const int* ll2       = (const int*)d_in[9];
    const int* amask     = (const int*)d_in[10];
    const float* W_dyn   = (const float*)d_in[11];
    const float* W_pmcat = (const float*)d_in[12];
    const float* W_time  = (const float*)d_in[13];
    const float* W_llctx = (const float*)d_in[14];
    const float* W_pmctx = (const float*)d_in[15];
    const float* W_rbctx = (const float*)d_in[16];
    const float* W_cc1   = (const float*)d_in[17];
    const float* b_cc1   = (const float*)d_in[18];
    const float* W_cc2   = (const float*)d_in[19];
    const float* b_cc2   = (const float*)d_in[20];
    const float* Wq      = (const float*)d_in[21];
    const float* Wk      = (const float*)d_in[22];
    const float* Wv      = (const float*)d_in[23];
    const float* Wshk    = (const float*)d_in[24];
    const float* W_mhc   = (const float*)d_in[25];
    const float* b_mhc   = (const float*)d_in[26];
    (void)in_sizes; (void)n_in; (void)out_size; (void)ws_size;

    float* w = (float*)d_ws;
    size_t off = 0;
    auto alloc = [&](size_t n) { float* p = w + off; off += n; return p; };

    float* dallA  = alloc((size_t)B_ * A_);
    float* remain = alloc((size_t)B_ * P_);
    int*   idxs   = (int*)alloc((size_t)B_ * P_);
    float* cvec   = alloc(2048);
    float* Gll    = alloc((size_t)B_ * 1024);
    float* colemb = alloc((size_t)B_ * NS_ * D_);
    float* E      = alloc((size_t)B_ * A_ * D_);
    float* KVS    = alloc((size_t)B_ * A_ * 1536);
    float* Xpm    = alloc((size_t)B_ * D_);
    float* Xrb    = alloc((size_t)B_ * D_);
    float* ctx    = alloc((size_t)B_ * 3 * D_);
    float* hid    = alloc((size_t)B_ * D_);
    float* ctxout = alloc((size_t)B_ * D_);
    float* Qb     = alloc((size_t)B_ * D_);
    float* OUTb   = alloc((size_t)B_ * D_);
    float* MHb    = alloc((size_t)B_ * D_);
    unsigned short* Cpack = (unsigned short*)alloc((size_t)B_ * NS_ * 512 / 2);
    unsigned short* Gpack = (unsigned short*)alloc((size_t)B_ * A_ * 512 / 2);
    unsigned short* Epack = (unsigned short*)alloc((size_t)B_ * A_ * 512 / 2);
    unsigned short* Wpack = (unsigned short*)alloc((size_t)(2 * 524288 + 2 * 1572864) / 2);

    const unsigned short* Wp1   = Wpack;
    const unsigned short* Wp2   = Wpack + 524288;
    const unsigned short* Wkvs1 = Wpack + 1048576;
    const unsigned short* Wkvs2 = Wpack + 1048576 + 1572864;

    {
        ProCfg c{W_pmcat, Wk, Wv, Wshk, Wpack,
                 enc_col, Cpack,
                 W_dyn, W_time, cvec,
                 clockp, lpet, loc_id, robot_loc, lhw, lstage,
                 dallA, remain, idxs,
                 enc_row, ll1, ll2, Gpack, Gll};
        prologue_kernel<<<25872, 128, 0, stream>>>(c);
    }

    // colemb = enc_col @ Wp1^T   (M = 4096 = 16 * 256)
    {
        GemmCfg c{};
        c.pr[0] = {Cpack, Wp1};
        c.npair = 1; c.C = colemb; c.ldc = 512;
        gemm_mfma<<<dim3(4, (B_ * NS_) / 256), 256, 0, stream>>>(c);
    }
    // E = G @ Wp2^T with fused assemble epilogue   (M = 17408 = 68 * 256)
    {
        GemmCfg c{};
        c.pr[0] = {Gpack, Wp2};
        c.npair = 1; c.C = E; c.ldc = 512;
        c.fuseE = 1; c.colemb = colemb; c.c_pm = cvec; c.remain = remain;
        c.idxs = idxs; c.Epack = Epack;
        gemm_mfma<<<dim3(4, (B_ * A_) / 256), 256, 0, stream>>>(c);
    }
    // KVS merged GEMM
    {
        GemmCfg c{};
        c.pr[0] = {Gpack, Wkvs2};
        c.pr[1] = {Epack, Wkvs1};
        c.npair = 2; c.C = KVS; c.ldc = 1536;
        c.r1row = dallA; c.r1col = cvec + 512;
        gemm_mfma<<<dim3(12, (B_ * A_) / 256), 256, 0, stream>>>(c);
    }

    meanrb_kernel<<<B_, 128, 0, stream>>>(E, robot_loc, Xpm, Xrb);

    {
        Ctx3Cfg c{Gll, Xpm, Xrb, W_llctx, W_pmctx, W_rbctx, ctx};
        ctx3_kernel<<<dim3(8, 8, 3), 256, 0, stream>>>(c);
    }
    gemm_nt<<<dim3(8, 8), 256, 0, stream>>>(ctx, 3 * D_, W_cc1, 3 * D_, hid, D_,
                                            3 * D_, b_cc1, 1);
    gemm_nt<<<dim3(8, 8), 256, 0, stream>>>(hid, D_, W_cc2, D_, ctxout, D_,
                                            D_, b_cc2, 0);
    gemm_nt<<<dim3(8, 8), 256, 0, stream>>>(ctxout, D_, Wq, D_, Qb, D_,
                                            D_, nullptr, 0);

    attn_kernel<<<8192, 64, 0, stream>>>(Qb, KVS, amask, OUTb);

    gemm_nt<<<dim3(8, 8), 256, 0, stream>>>(OUTb, D_, W_mhc, D_, MHb, D_,
                                            D_, b_mhc, 0);

    final_kernel<<<B_, 320, 0, stream>>>(MHb, KVS, amask, (float*)d_out);
}

// Round 7
// 790.807 us; speedup vs baseline: 1.2015x; 1.2015x over previous
//
#include <hip/hip_runtime.h>
#include <hip/hip_bf16.h>

// CONCATNet forward. B=512 NW=256 NS=8 P=32 D=512 H=16 QK=32 A=34
// R12: revert gemm_mfma to R10 geometry + 32x64 small-GEMM tiles.
//  - R11 post-mortem: 256x128 tile (248 VGPR, 64KB LDS) -> 1 block/CU
//    (Occupancy 18->9%); drain fully exposed, KVS 155->206us. Reverted.
//  - Budget calibration: 2x 1GiB poison fills (162us each) are inside the
//    timed window (~324us fixed). Remaining controllable ~520us at R10 =
//    ~187 MFMA GEMMs + ~330 rest; largest modellable block is the serial
//    fp32 GEMM chain (ctx3->cc1->cc2->q->mhc) at 64 blocks/launch = 25% CU
//    coverage, ~165us. Fix: BM 64->32 (grid 16x8=128 blocks) -> chain wall
//    roughly halves. Accumulation order over k unchanged -> bit-identical.
// R10: BK=64 (halved per-K-step fixed drain cost), 48KB LDS, 2-3 blocks/CU.
// R9: fp16 2-pass split GEMM (A single fp16, W split hi/lo). absmax 2^-10.
// R6: fused split passes + bijective XCD block remap (FETCH 447->137MB).
// action_mask arrives as int32 (harness widens bool).

#define B_  512
#define NW_ 256
#define NS_ 8
#define P_  32
#define D_  512
#define H_  16
#define QK_ 32
#define A_  34

typedef __attribute__((ext_vector_type(8))) _Float16 half8;
typedef __attribute__((ext_vector_type(4))) float floatx4;

// ---------------------------------------------------------------- fp16 helpers
__device__ __forceinline__ unsigned short f16b(float x) {
    _Float16 h = (_Float16)x;
    union { _Float16 f; unsigned short u; } c; c.f = h; return c.u;
}
__device__ __forceinline__ void f16_split(float x, unsigned short& hi, unsigned short& lo) {
    _Float16 h = (_Float16)x;
    _Float16 l = (_Float16)(x - (float)h);
    union { _Float16 f; unsigned short u; } c;
    c.f = h; hi = c.u; c.f = l; lo = c.u;
}

__device__ __forceinline__ void gload16(const void* g, void* l) {
    __builtin_amdgcn_global_load_lds(
        (const __attribute__((address_space(1))) void*)g,
        (__attribute__((address_space(3))) void*)l, 16, 0, 0);
}

// ---------------------------------------------------------------- MFMA GEMM
// A buffers: single fp16, row stride 512 shorts.
// W buffers: split fp16, row stride 1024 shorts (hi at +0, lo at +512).
struct Pair { const unsigned short* a; const unsigned short* w; };
struct GemmCfg {
    Pair pr[2];
    int npair;
    float* C;
    int ldc;
    const float* r1row;
    const float* r1col;
    int fuseE;
    const float* colemb;
    const float* c_pm;
    const float* remain;
    const int* idxs;
    unsigned short* Epack;
};

__global__ __launch_bounds__(256) void gemm_mfma(GemmCfg cfg)
{
    // BK=64: 128 rows x 64 shorts per class = 16 KB; 3 classes = 48 KB
    __shared__ __align__(16) unsigned short As [128 * 64];
    __shared__ __align__(16) unsigned short WsH[128 * 64];
    __shared__ __align__(16) unsigned short WsL[128 * 64];

    const int tid  = threadIdx.x;

    // XCD-aware bijective block remap (m204)
    int lid = blockIdx.y * gridDim.x + blockIdx.x;
    {
        const int nwg = gridDim.x * gridDim.y;
        const int xcd = lid & 7, o = lid >> 3;
        const int qq = nwg >> 3, rr = nwg & 7;
        lid = (xcd < rr ? xcd * (qq + 1) : rr * (qq + 1) + (xcd - rr) * qq) + o;
    }
    const int m0 = (lid / gridDim.x) * 128;
    const int n0 = (lid % gridDim.x) * 128;

    const int wave = tid >> 6;
    const int lane = tid & 63;
    const int wr   = wave >> 1;
    const int wc   = wave & 1;
    // staging: 256 threads cover 32 rows x 8 chunks per round; 4 rounds/class
    const int srow  = tid >> 3;
    const int lpart = (((tid & 7) ^ (srow & 7)) << 3); // permuted global chunk

    floatx4 acc[4][4];
#pragma unroll
    for (int i = 0; i < 4; i++)
#pragma unroll
        for (int j = 0; j < 4; j++) acc[i][j] = (floatx4)0.f;

    const int q = lane >> 4;
    const int r = lane & 15;
    // stored position of global chunk (s*4+q) in row (..+r): XOR with row&7
    const int qs0 = (((q    ) ^ (r & 7)) << 3);
    const int qs1 = (((q + 4) ^ (r & 7)) << 3);

    for (int pi = 0; pi < cfg.npair; ++pi) {
        const unsigned short* Ab = cfg.pr[pi].a + (size_t)(m0 + srow) * 512 + lpart;
        const unsigned short* Wb = cfg.pr[pi].w + (size_t)(n0 + srow) * 1024 + lpart;
        for (int k0 = 0; k0 < 512; k0 += 64) {
            __syncthreads();
#pragma unroll
            for (int rd = 0; rd < 4; rd++) {
                gload16(Ab + (size_t)rd * (32 * 512)  + k0,       &As [rd * 2048 + tid * 8]);
                gload16(Wb + (size_t)rd * (32 * 1024) + k0,       &WsH[rd * 2048 + tid * 8]);
                gload16(Wb + (size_t)rd * (32 * 1024) + k0 + 512, &WsL[rd * 2048 + tid * 8]);
            }
            __syncthreads();

#pragma unroll
            for (int s = 0; s < 2; s++) {
                const int qs = s ? qs1 : qs0;
                half8 af[4], wh[4], wl[4];
#pragma unroll
                for (int i = 0; i < 4; i++)
                    af[i] = *(const half8*)&As[(wr * 64 + i * 16 + r) * 64 + qs];
#pragma unroll
                for (int j = 0; j < 4; j++) {
                    wh[j] = *(const half8*)&WsH[(wc * 64 + j * 16 + r) * 64 + qs];
                    wl[j] = *(const half8*)&WsL[(wc * 64 + j * 16 + r) * 64 + qs];
                }
                // A x W_hi
#pragma unroll
                for (int i = 0; i < 4; i++)
#pragma unroll
                    for (int j = 0; j < 4; j++)
                        acc[i][j] = __builtin_amdgcn_mfma_f32_16x16x32_f16(
                            af[i], wh[j], acc[i][j], 0, 0, 0);
                // A x W_lo
#pragma unroll
                for (int i = 0; i < 4; i++)
#pragma unroll
                    for (int j = 0; j < 4; j++)
                        acc[i][j] = __builtin_amdgcn_mfma_f32_16x16x32_f16(
                            af[i], wl[j], acc[i][j], 0, 0, 0);
            }
        }
    }

    if (cfg.fuseE) {
#pragma unroll
        for (int j = 0; j < 4; j++) {
            const int col = n0 + wc * 64 + j * 16 + r;
            const float cpm = cfg.c_pm[col];
#pragma unroll
            for (int i = 0; i < 4; i++) {
                const int rowb = m0 + wr * 64 + i * 16 + q * 4;
#pragma unroll
                for (int reg = 0; reg < 4; reg++) {
                    const int m = rowb + reg;
                    const int b = m / A_;
                    const int a = m - b * A_;
                    float v = 0.f;
                    if (a >= 2) {
                        const int p = a - 2;
                        const int s = cfg.idxs[b * P_ + p];
                        v = acc[i][j][reg]
                          + cfg.colemb[((size_t)(b * NS_ + s)) * 512 + col]
                          + cfg.remain[b * P_ + p] * cpm;
                    }
                    cfg.C[(size_t)m * 512 + col] = v;
                    cfg.Epack[(size_t)m * 512 + col] = f16b(v);
                }
            }
        }
    } else {
#pragma unroll
        for (int j = 0; j < 4; j++) {
            const int col = n0 + wc * 64 + j * 16 + r;
            const float r1c = cfg.r1col ? cfg.r1col[col] : 0.f;
#pragma unroll
            for (int i = 0; i < 4; i++) {
                const int rowb = m0 + wr * 64 + i * 16 + q * 4;
#pragma unroll
                for (int reg = 0; reg < 4; reg++) {
                    float v = acc[i][j][reg];
                    if (cfg.r1row) v += cfg.r1row[rowb + reg] * r1c;
                    cfg.C[(size_t)(rowb + reg) * cfg.ldc + col] = v;
                }
            }
        }
    }
}

// ---------------------------------------------------------------- fp32 GEMM (small)
// 32x64 tile: 128 blocks for 512x512 -> 2x CU coverage vs 64x64.
#define BM 32
#define BN 64
#define BK 32
__device__ __forceinline__ void gemm_nt_body(
    const float* __restrict__ A, int lda,
    const float* __restrict__ W, int ldw,
    float* __restrict__ C, int ldc,
    int K, const float* __restrict__ bias, int relu,
    int m0, int n0)
{
    __shared__ float As[BK][BM + 2];
    __shared__ float Wsm[BK][BN + 4];

    const int tid = threadIdx.x;
    const int ty = tid >> 4;          // 0..15 -> 2 rows each
    const int tx = tid & 15;          // 0..15 -> 4 cols each
    const int arow = tid >> 3;        // 0..31
    const int acol = (tid & 7) << 2;  // 0..28
    const int wrow = tid >> 2;        // 0..63
    const int wcol = (tid & 3) << 3;  // 0,8,16,24

    float acc[2][4];
#pragma unroll
    for (int i = 0; i < 2; i++)
#pragma unroll
        for (int j = 0; j < 4; j++) acc[i][j] = 0.f;

    const float* Ablk = A + (size_t)m0 * lda;
    const float* Wblk = W + (size_t)n0 * ldw;

    for (int k0 = 0; k0 < K; k0 += BK) {
        const float4 a0 = *(const float4*)(Ablk + (size_t)arow * lda + k0 + acol);
        const float4 w0 = *(const float4*)(Wblk + (size_t)wrow * ldw + k0 + wcol);
        const float4 w1 = *(const float4*)(Wblk + (size_t)wrow * ldw + k0 + wcol + 4);

        __syncthreads();
        As[acol + 0][arow] = a0.x; As[acol + 1][arow] = a0.y;
        As[acol + 2][arow] = a0.z; As[acol + 3][arow] = a0.w;
        Wsm[wcol + 0][wrow] = w0.x; Wsm[wcol + 1][wrow] = w0.y;
        Wsm[wcol + 2][wrow] = w0.z; Wsm[wcol + 3][wrow] = w0.w;
        Wsm[wcol + 4][wrow] = w1.x; Wsm[wcol + 5][wrow] = w1.y;
        Wsm[wcol + 6][wrow] = w1.z; Wsm[wcol + 7][wrow] = w1.w;
        __syncthreads();

#pragma unroll
        for (int k = 0; k < BK; k++) {
            const float2 av = *(const float2*)(&As[k][ty << 1]);
            const float4 wv = *(const float4*)(&Wsm[k][tx << 2]);
            acc[0][0] += av.x * wv.x; acc[0][1] += av.x * wv.y;
            acc[0][2] += av.x * wv.z; acc[0][3] += av.x * wv.w;
            acc[1][0] += av.y * wv.x; acc[1][1] += av.y * wv.y;
            acc[1][2] += av.y * wv.z; acc[1][3] += av.y * wv.w;
        }
    }

    const int mbase = m0 + (ty << 1);
    const int nbase = n0 + (tx << 2);
    float4 bv = make_float4(0.f, 0.f, 0.f, 0.f);
    if (bias) bv = *(const float4*)(bias + nbase);

#pragma unroll
    for (int i = 0; i < 2; i++) {
        float* cp = C + (size_t)(mbase + i) * ldc + nbase;
        float4 v = make_float4(acc[i][0], acc[i][1], acc[i][2], acc[i][3]);
        if (bias) { v.x += bv.x; v.y += bv.y; v.z += bv.z; v.w += bv.w; }
        if (relu) {
            v.x = fmaxf(v.x, 0.f); v.y = fmaxf(v.y, 0.f);
            v.z = fmaxf(v.z, 0.f); v.w = fmaxf(v.w, 0.f);
        }
        *(float4*)cp = v;
    }
}

__global__ __launch_bounds__(256) void gemm_nt(
    const float* __restrict__ A, int lda,
    const float* __restrict__ W, int ldw,
    float* __restrict__ C, int ldc,
    int K, const float* __restrict__ bias, int relu)
{
    gemm_nt_body(A, lda, W, ldw, C, ldc, K, bias, relu,
                 blockIdx.y * BM, blockIdx.x * BN);
}

// ---------------------------------------------------------------- ctx 3-in-1
struct Ctx3Cfg {
    const float* A0; const float* A1; const float* A2;
    const float* W0; const float* W1; const float* W2;
    float* C;
};
__global__ __launch_bounds__(256) void ctx3_kernel(Ctx3Cfg cfg)
{
    const int z = blockIdx.z;
    const float* A = (z == 0) ? cfg.A0 : (z == 1) ? cfg.A1 : cfg.A2;
    const float* W = (z == 0) ? cfg.W0 : (z == 1) ? cfg.W1 : cfg.W2;
    const int K = (z == 0) ? 1024 : 512;
    gemm_nt_body(A, K, W, K, cfg.C + z * 512, 1536, K, nullptr, 0,
                 blockIdx.y * BM, blockIdx.x * BN);
}

// ---------------------------------------------------------------- fused prologue
// blocks [0,4096): packW | [4096,8192): packcol | [8192,8208): cvec |
// [8208,8464): prep (2 batch rows per block) | [8464,25872): gatherG
struct ProCfg {
    const float* Wp; const float* Wk; const float* Wv; const float* Wsh;
    unsigned short* Wpack;
    const float* enc_col; unsigned short* Cpack;
    const float* W_dyn; const float* W_time; float* cvec;
    const float* clockp; const float* lpet;
    const int* loc_id; const int* robot_loc; const int* lhw; const int* lstage;
    float* dallA; float* remain; int* idxs;
    const float* enc_row; const int* ll1; const int* ll2;
    unsigned short* Gpack; float* Gll;
};
__global__ __launch_bounds__(128) void prologue_kernel(ProCfg c)
{
    const int blk = blockIdx.x;
    const int tid = threadIdx.x;
    if (blk < 4096) {
        // ---- packW (fp16 split: hi + lo halves)
        const int row = blk & 511;
        const int ms = blk >> 9;
        const int mat = ms >> 1, seg = ms & 1;
        const int d = tid * 4;
        const float* src = (mat == 0 ? c.Wp : mat == 1 ? c.Wk : mat == 2 ? c.Wv : c.Wsh)
                           + (size_t)row * 1536 + seg * 512 + d;
        const float4 v = *(const float4*)src;
        unsigned short h0, h1, h2, h3, l0, l1, l2, l3;
        f16_split(v.x, h0, l0); f16_split(v.y, h1, l1);
        f16_split(v.z, h2, l2); f16_split(v.w, h3, l3);
        unsigned short* dst;
        if (mat == 0) {
            dst = c.Wpack + (size_t)seg * 524288 + (size_t)row * 1024 + d;
        } else {
            const int rr = (mat - 1) * 512 + row;
            dst = c.Wpack + 1048576 + (size_t)seg * 1572864 + (size_t)rr * 1024 + d;
        }
        *(ushort4*)dst = make_ushort4(h0, h1, h2, h3);
        *(ushort4*)(dst + 512) = make_ushort4(l0, l1, l2, l3);
    } else if (blk < 8192) {
        // ---- packcol (single fp16)
        const int row = blk - 4096;
        const int d = tid * 4;
        const float4 v = *(const float4*)(c.enc_col + (size_t)row * 512 + d);
        unsigned short* dp = c.Cpack + (size_t)row * 512 + d;
        *(ushort4*)dp = make_ushort4(f16b(v.x), f16b(v.y), f16b(v.z), f16b(v.w));
    } else if (blk < 8208) {
        // ---- cvec
        const int id = (blk - 8192) * 128 + tid;
        const int vec = id >> 9;
        const int h = id & 511;
        float s = 0.f;
        if (vec == 0) {
            const float* wp = c.Wp + (size_t)h * 1536 + 1024;
            for (int j = 0; j < 512; j++) s += c.W_dyn[j * 2] * wp[j];
        } else {
            const float* Wm = (vec == 1) ? c.Wk : (vec == 2) ? c.Wv : c.Wsh;
            const float* wp = Wm + (size_t)h * 1536 + 1024;
            for (int j = 0; j < 512; j++) s += c.W_time[j] * wp[j];
        }
        c.cvec[id] = s;
    } else if (blk < 8464) {
        // ---- prep (2 batch rows / block)
        const int b = (blk - 8208) * 2 + (tid >> 6);
        const int t = tid & 63;
        const float ck = c.clockp[b];
        const int rb = c.robot_loc[b];
        if (t < P_) {
            const float endt = c.lpet[b * P_ + t];
            const int lid = c.loc_id[b * P_ + t];
            const float pk = ck + 3.f * (lid != rb ? 1.f : 0.f);
            c.dallA[b * A_ + 2 + t] = (fmaxf(endt, pk) + 9.f - ck) * (1.f / 300.f);
            c.remain[b * P_ + t] = fmaxf(endt - ck, 0.f) * (1.f / 300.f);
            c.idxs[b * P_ + t] = c.lstage[b * P_ + t] - 1;
        } else if (t == P_) {
            const float d0 = (3.f * (rb != 0 ? 1.f : 0.f) + 9.f) * (1.f / 300.f);
            c.dallA[b * A_ + 0] = d0;
            c.dallA[b * A_ + 1] = d0;
        }
    } else {
        // ---- gatherG (idxw computed inline from lhw)
        const int ba = blk - 8464;
        const int b = ba / A_, a = ba % A_;
        const int d = tid * 4;
        int row;
        if (a == 0) row = c.ll1[b];
        else if (a == 1) row = c.ll2[b];
        else {
            const int w = c.lhw[b * P_ + a - 2];
            row = (w >= 0) ? w : NW_;
        }
        float4 v = make_float4(0.f, 0.f, 0.f, 0.f);
        if (row < NW_) v = *(const float4*)(c.enc_row + ((size_t)b * NW_ + row) * D_ + d);
        unsigned short* dp = c.Gpack + (size_t)ba * 512 + d;
        *(ushort4*)dp = make_ushort4(f16b(v.x), f16b(v.y), f16b(v.z), f16b(v.w));
        if (a < 2) *(float4*)(c.Gll + (size_t)b * 1024 + a * 512 + d) = v;
    }
}

// ---------------------------------------------------------------- mean + rb gather
__global__ __launch_bounds__(128) void meanrb_kernel(
    const float* __restrict__ E, const int* __restrict__ robot_loc,
    float* __restrict__ Xpm, float* __restrict__ Xrb)
{
    const int b = blockIdx.x;
    const int d = threadIdx.x * 4;
    const float* ep = E + ((size_t)b * A_ + 2) * D_ + d;
    float4 acc = make_float4(0.f, 0.f, 0.f, 0.f);
    for (int p = 0; p < P_; p++) {
        const float4 v = *(const float4*)(ep + (size_t)p * D_);
        acc.x += v.x; acc.y += v.y; acc.z += v.z; acc.w += v.w;
    }
    const float inv = 1.f / (float)P_;
    acc.x *= inv; acc.y *= inv; acc.z *= inv; acc.w *= inv;
    *(float4*)(Xpm + (size_t)b * D_ + d) = acc;
    const int rb = robot_loc[b];
    *(float4*)(Xrb + (size_t)b * D_ + d) =
        *(const float4*)(E + ((size_t)b * A_ + 2 + rb) * D_ + d);
}

// ---------------------------------------------------------------- attention
// linear grid 8192 = B*H, XCD chunk remap so all 16 heads of a batch land on
// the same XCD's L2 (they share that batch's K/V lines).
__global__ __launch_bounds__(64) void attn_kernel(
    const float* __restrict__ Q, const float* __restrict__ KVS,
    const int* __restrict__ mask, float* __restrict__ OUT)
{
    const int L = blockIdx.x;
    const int lid = ((L & 7) << 10) + (L >> 3);   // 8192 = 8 * 1024, bijective
    const int b = lid >> 4;
    const int h = lid & 15;
    const int lane = threadIdx.x;
    __shared__ float w[A_];
    float s;
    if (lane < A_) {
        const float* qp = Q + (size_t)b * D_ + h * QK_;
        const float* kp = KVS + ((size_t)b * A_ + lane) * 1536 + h * QK_;
        float acc = 0.f;
#pragma unroll
        for (int i = 0; i < QK_; i += 4) {
            const float4 qv = *(const float4*)(qp + i);
            const float4 kv = *(const float4*)(kp + i);
            acc += qv.x * kv.x + qv.y * kv.y + qv.z * kv.z + qv.w * kv.w;
        }
        s = acc * 0.17677669529663687f;
        if (!mask[b * A_ + lane]) s += -1e10f;
    } else {
        s = -1e30f;
    }
    float m = s;
    for (int o = 32; o; o >>= 1) m = fmaxf(m, __shfl_xor(m, o));
    float p = (lane < A_) ? expf(s - m) : 0.f;
    float sum = p;
    for (int o = 32; o; o >>= 1) sum += __shfl_xor(sum, o);
    if (lane < A_) w[lane] = p / sum;
    __syncthreads();
    if (lane < QK_) {
        const float* vp = KVS + (size_t)b * A_ * 1536 + 512 + h * QK_ + lane;
        float acc = 0.f;
#pragma unroll 2
        for (int a = 0; a < A_; a++) acc += w[a] * vp[(size_t)a * 1536];
        OUT[(size_t)b * D_ + h * QK_ + lane] = acc;
    }
}

// ---------------------------------------------------------------- final
__global__ __launch_bounds__(320) void final_kernel(
    const float* __restrict__ MH, const float* __restrict__ KVS,
    const int* __restrict__ mask, float* __restrict__ out)
{
    const int b = blockIdx.x;
    const int t = threadIdx.x;
    __shared__ float mh[D_];
    __shared__ float sc[A_];
    for (int i = t; i < D_; i += 320) mh[i] = MH[(size_t)b * D_ + i];
    __syncthreads();
    const int a = t >> 3;
    const int part = t & 7;
    float s = 0.f;
    if (a < A_) {
        const float* sp = KVS + ((size_t)b * A_ + a) * 1536 + 1024 + part * 64;
        const float* mp = mh + part * 64;
#pragma unroll
        for (int i = 0; i < 64; i += 4) {
            const float4 v = *(const float4*)(sp + i);
            s += mp[i] * v.x + mp[i + 1] * v.y + mp[i + 2] * v.z + mp[i + 3] * v.w;
        }
    }
    s += __shfl_down(s, 4, 8);
    s += __shfl_down(s, 2, 8);
    s += __shfl_down(s, 1, 8);
    if (a < A_ && part == 0) {
        float v = 10.f * tanhf(s * 0.044194173824159216f);
        if (!mask[b * A_ + a]) v += -1e10f;
        sc[a] = v;
    }
    __syncthreads();
    if (t < 64) {
        float x = (t < A_) ? sc[t] : -1e30f;
        float m = x;
        for (int o = 32; o; o >>= 1) m = fmaxf(m, __shfl_xor(m, o));
        float p = (t < A_) ? expf(x - m) : 0.f;
        float sum = p;
        for (int o = 32; o; o >>= 1) sum += __shfl_xor(sum, o);
        if (t < A_) out[(size_t)b * A_ + t] = p / sum;
    }
}

// ---------------------------------------------------------------- launcher
extern "C" void kernel_launch(void* const* d_in, const int* in_sizes, int n_in,
                              void* d_out, int out_size, void* d_ws, size_t ws_size,
                              hipStream_t stream)
{
    const float* enc_row = (const float*)d_in[0];
    const float* enc_col = (const float*)d_in[1];
    const float* clockp  = (const float*)d_in[2];
    const float* lpet    = (const float*)d_in[3];
    const int* loc_id    = (const int*)d_in[4];
    const int* robot_loc = (const int*)d_in[5];
    const int* lhw       = (const int*)d_in[6];
    const int* lstage    = (const int*)d_in[7];
    const int* ll1       = (const int*)d_in[8];
    const int* ll2       = (const int*)d_in[9];
    const int* amask     = (const int*)d_in[10];
    const float* W_dyn   = (const float*)d_in[11];
    const float* W_pmcat = (const float*)d_in[12];
    const float* W_time  = (const float*)d_in[13];
    const float* W_llctx = (const float*)d_in[14];
    const float* W_pmctx = (const float*)d_in[15];
    const float* W_rbctx = (const float*)d_in[16];
    const float* W_cc1   = (const float*)d_in[17];
    const float* b_cc1   = (const float*)d_in[18];
    const float* W_cc2   = (const float*)d_in[19];
    const float* b_cc2   = (const float*)d_in[20];
    const float* Wq      = (const float*)d_in[21];
    const float* Wk      = (const float*)d_in[22];
    const float* Wv      = (const float*)d_in[23];
    const float* Wshk    = (const float*)d_in[24];
    const float* W_mhc   = (const float*)d_in[25];
    const float* b_mhc   = (const float*)d_in[26];
    (void)in_sizes; (void)n_in; (void)out_size; (void)ws_size;

    float* w = (float*)d_ws;
    size_t off = 0;
    auto alloc = [&](size_t n) { float* p = w + off; off += n; return p; };

    float* dallA  = alloc((size_t)B_ * A_);
    float* remain = alloc((size_t)B_ * P_);
    int*   idxs   = (int*)alloc((size_t)B_ * P_);
    float* cvec   = alloc(2048);
    float* Gll    = alloc((size_t)B_ * 1024);
    float* colemb = alloc((size_t)B_ * NS_ * D_);
    float* E      = alloc((size_t)B_ * A_ * D_);
    float* KVS    = alloc((size_t)B_ * A_ * 1536);
    float* Xpm    = alloc((size_t)B_ * D_);
    float* Xrb    = alloc((size_t)B_ * D_);
    float* ctx    = alloc((size_t)B_ * 3 * D_);
    float* hid    = alloc((size_t)B_ * D_);
    float* ctxout = alloc((size_t)B_ * D_);
    float* Qb     = alloc((size_t)B_ * D_);
    float* OUTb   = alloc((size_t)B_ * D_);
    float* MHb    = alloc((size_t)B_ * D_);
    unsigned short* Cpack = (unsigned short*)alloc((size_t)B_ * NS_ * 512 / 2);
    unsigned short* Gpack = (unsigned short*)alloc((size_t)B_ * A_ * 512 / 2);
    unsigned short* Epack = (unsigned short*)alloc((size_t)B_ * A_ * 512 / 2);
    unsigned short* Wpack = (unsigned short*)alloc((size_t)(2 * 524288 + 2 * 1572864) / 2);

    const unsigned short* Wp1   = Wpack;
    const unsigned short* Wp2   = Wpack + 524288;
    const unsigned short* Wkvs1 = Wpack + 1048576;
    const unsigned short* Wkvs2 = Wpack + 1048576 + 1572864;

    {
        ProCfg c{W_pmcat, Wk, Wv, Wshk, Wpack,
                 enc_col, Cpack,
                 W_dyn, W_time, cvec,
                 clockp, lpet, loc_id, robot_loc, lhw, lstage,
                 dallA, remain, idxs,
                 enc_row, ll1, ll2, Gpack, Gll};
        prologue_kernel<<<25872, 128, 0, stream>>>(c);
    }

    // colemb = enc_col @ Wp1^T
    {
        GemmCfg c{};
        c.pr[0] = {Cpack, Wp1};
        c.npair = 1; c.C = colemb; c.ldc = 512;
        gemm_mfma<<<dim3(4, (B_ * NS_) / 128), 256, 0, stream>>>(c);
    }
    // E = G @ Wp2^T with fused assemble epilogue
    {
        GemmCfg c{};
        c.pr[0] = {Gpack, Wp2};
        c.npair = 1; c.C = E; c.ldc = 512;
        c.fuseE = 1; c.colemb = colemb; c.c_pm = cvec; c.remain = remain;
        c.idxs = idxs; c.Epack = Epack;
        gemm_mfma<<<dim3(4, (B_ * A_) / 128), 256, 0, stream>>>(c);
    }
    // KVS merged GEMM
    {
        GemmCfg c{};
        c.pr[0] = {Gpack, Wkvs2};
        c.pr[1] = {Epack, Wkvs1};
        c.npair = 2; c.C = KVS; c.ldc = 1536;
        c.r1row = dallA; c.r1col = cvec + 512;
        gemm_mfma<<<dim3(12, (B_ * A_) / 128), 256, 0, stream>>>(c);
    }

    meanrb_kernel<<<B_, 128, 0, stream>>>(E, robot_loc, Xpm, Xrb);

    {
        Ctx3Cfg c{Gll, Xpm, Xrb, W_llctx, W_pmctx, W_rbctx, ctx};
        ctx3_kernel<<<dim3(8, 16, 3), 256, 0, stream>>>(c);
    }
    gemm_nt<<<dim3(8, 16), 256, 0, stream>>>(ctx, 3 * D_, W_cc1, 3 * D_, hid, D_,
                                             3 * D_, b_cc1, 1);
    gemm_nt<<<dim3(8, 16), 256, 0, stream>>>(hid, D_, W_cc2, D_, ctxout, D_,
                                             D_, b_cc2, 0);
    gemm_nt<<<dim3(8, 16), 256, 0, stream>>>(ctxout, D_, Wq, D_, Qb, D_,
                                             D_, nullptr, 0);

    attn_kernel<<<8192, 64, 0, stream>>>(Qb, KVS, amask, OUTb);

    gemm_nt<<<dim3(8, 16), 256, 0, stream>>>(OUTb, D_, W_mhc, D_, MHb, D_,
                                             D_, b_mhc, 0);

    final_kernel<<<B_, 320, 0, stream>>>(MHb, KVS, amask, (float*)d_out);
}